// Round 1
// baseline (1568.023 us; speedup 1.0000x reference)
//
#include <hip/hip_runtime.h>
#include <hip/hip_cooperative_groups.h>

namespace cg = cooperative_groups;

// LDN cell: new_state = expm(A) @ state + [inv(A)(expm(A)-I)B] x^T
// expm via scaling-and-squaring Taylor-16 (Paterson-Stockmeyer) on the
// augmented [[A,B],[0,0]] padded to 576 (theta=2, 15 squarings).
// Chain matrices stored as 3-plane bf16 (hi/mid/lo, f32-equivalent via 6 MFMA
// products) in BOTH orientations; chain scratch lives in d_out (fully
// overwritten by the final GEMM).
// THIS VERSION: the whole chain (build + 21 GEMMs + combine + conv) is ONE
// cooperative kernel with grid.sync() between stages — the 24 dependent
// dispatch boundaries (~35 us each: AQL barrier + L2 wb/inv + ramp) were
// ~70% of total time. Main GEMM unchanged.

#define PDIM 576
#define PP (PDIM * PDIM)
#define QDIM 512
#define NDIM 65536
#define LSTR 40   // LDS row stride in halfwords (80 B)
#define NBLK 81
#define NTHR 256
#define GSTRIDE (NBLK * NTHR)   // 20736

typedef __attribute__((ext_vector_type(8))) short short8;
typedef __attribute__((ext_vector_type(4))) short short4v;
typedef __attribute__((ext_vector_type(4))) float f32x4;
typedef unsigned short u16;

__device__ __forceinline__ short f2bf(float f) {  // RNE bf16
  unsigned u = __builtin_bit_cast(unsigned, f);
  u += 0x7fffu + ((u >> 16) & 1u);
  return (short)(u >> 16);
}
__device__ __forceinline__ float bf2f(short s) {
  unsigned u = ((unsigned)(unsigned short)s) << 16;
  return __builtin_bit_cast(float, u);
}
__device__ __forceinline__ void split3(float v, short& h, short& m, short& l) {
  h = f2bf(v);
  float r1 = v - bf2f(h);
  m = f2bf(r1);
  float r2 = r1 - bf2f(m);
  l = f2bf(r2);
}
__device__ __forceinline__ f32x4 MFMA(short8 a, short8 b, f32x4 c) {
  return __builtin_amdgcn_mfma_f32_16x16x32_bf16(a, b, c, 0, 0, 0);
}

// ------------------------------------------------- chain GEMM stage ---------
// Out = X*Y (+ cI*I + c1*E1 + c2*E2 + c3*E3).  X: row-major planes, Y:
// col-major planes.  flags: 1=write rows planes, 2=write cols planes,
// 4=write f32, 8=add E terms.  64x64 tile, 4 waves of 32x32, BK=32.
__device__ __attribute__((noinline)) void gemm_stage(
    const u16* Xr, const u16* Yc, u16* Or, u16* Oc, float* Of,
    const float* E1, const float* E2, const float* E3,
    float cI, float c1, float c2, float c3, int flags, char* lraw) {
  short (*Xs)[64][LSTR] = (short(*)[64][LSTR])lraw;              // [3][64][40]
  short (*Ys)[64][LSTR] = (short(*)[64][LSTR])(lraw + 15360);
  float (*tb)[32][33] = (float(*)[32][33])lraw;                  // [4][32][33]
  const int tid = threadIdx.x;
  const int lane = tid & 63, w = tid >> 6;
  const int m0 = (blockIdx.x / 9) * 64, n0 = (blockIdx.x % 9) * 64;
  const int moff = (w >> 1) * 32, noff = (w & 1) * 32;
  const int l15 = lane & 15, quad = lane >> 4;
  f32x4 acc[2][2] = {};
  const int srow = tid >> 2, skc = (tid & 3) * 8;

  uint4 px[3], py[3];
#pragma unroll
  for (int pl = 0; pl < 3; pl++) {
    px[pl] = *(const uint4*)&Xr[(size_t)pl * PP + (m0 + srow) * PDIM + skc];
    py[pl] = *(const uint4*)&Yc[(size_t)pl * PP + (n0 + srow) * PDIM + skc];
  }

  for (int kb = 0; kb < PDIM; kb += 32) {
#pragma unroll
    for (int pl = 0; pl < 3; pl++) {
      *(uint4*)&Xs[pl][srow][skc] = px[pl];
      *(uint4*)&Ys[pl][srow][skc] = py[pl];
    }
    __syncthreads();
    if (kb + 32 < PDIM) {
#pragma unroll
      for (int pl = 0; pl < 3; pl++) {
        px[pl] = *(const uint4*)&Xr[(size_t)pl * PP + (m0 + srow) * PDIM + kb + 32 + skc];
        py[pl] = *(const uint4*)&Yc[(size_t)pl * PP + (n0 + srow) * PDIM + kb + 32 + skc];
      }
    }
    short8 xa[3][2], yb[3][2];
#pragma unroll
    for (int pl = 0; pl < 3; pl++) {
#pragma unroll
      for (int i = 0; i < 2; i++)
        xa[pl][i] = *(const short8*)&Xs[pl][moff + i * 16 + l15][quad * 8];
#pragma unroll
      for (int j = 0; j < 2; j++)
        yb[pl][j] = *(const short8*)&Ys[pl][noff + j * 16 + l15][quad * 8];
    }
#pragma unroll
    for (int i = 0; i < 2; i++)
#pragma unroll
      for (int j = 0; j < 2; j++) {
        f32x4 a = acc[i][j];
        a = MFMA(xa[0][i], yb[0][j], a);
        a = MFMA(xa[0][i], yb[1][j], a);
        a = MFMA(xa[1][i], yb[0][j], a);
        a = MFMA(xa[0][i], yb[2][j], a);
        a = MFMA(xa[2][i], yb[0][j], a);
        a = MFMA(xa[1][i], yb[1][j], a);
        acc[i][j] = a;
      }
    __syncthreads();
  }

  // ---- epilogue ----
  if (flags & 8) {  // E-term additions (coalesced 4B reads, L2-hot)
#pragma unroll
    for (int i = 0; i < 2; i++)
#pragma unroll
      for (int j = 0; j < 2; j++)
#pragma unroll
        for (int r = 0; r < 4; r++) {
          const int grow = m0 + moff + i * 16 + quad * 4 + r;
          const int gcol = n0 + noff + j * 16 + l15;
          const size_t idx = (size_t)grow * PDIM + gcol;
          float add = c1 * E1[idx] + c2 * E2[idx] + c3 * E3[idx];
          if (grow == gcol) add += cI;
          acc[i][j][r] += add;
        }
  }
  if (flags & 2) {  // cols planes straight from C-layout (4 consecutive m)
#pragma unroll
    for (int i = 0; i < 2; i++)
#pragma unroll
      for (int j = 0; j < 2; j++) {
        short4v hv, mv, lv;
#pragma unroll
        for (int r = 0; r < 4; r++) {
          short h, m, l; split3(acc[i][j][r], h, m, l);
          hv[r] = h; mv[r] = m; lv[r] = l;
        }
        const size_t b = (size_t)(n0 + noff + j * 16 + l15) * PDIM +
                         m0 + moff + i * 16 + quad * 4;
        *(short4v*)&Oc[b] = hv;
        *(short4v*)&Oc[PP + b] = mv;
        *(short4v*)&Oc[2 * PP + b] = lv;
      }
  }
  if (flags & 5) {  // rows planes / f32 via per-wave LDS transpose
#pragma unroll
    for (int i = 0; i < 2; i++)
#pragma unroll
      for (int j = 0; j < 2; j++)
#pragma unroll
        for (int r = 0; r < 4; r++)
          tb[w][i * 16 + quad * 4 + r][j * 16 + l15] = acc[i][j][r];
    const int ml = lane & 31, ns = lane >> 5;
    float vv[16];
#pragma unroll
    for (int e = 0; e < 16; e++) vv[e] = tb[w][ml][ns * 16 + e];
    const size_t rb = (size_t)(m0 + moff + ml) * PDIM + n0 + noff + ns * 16;
    if (flags & 4) {
#pragma unroll
      for (int g = 0; g < 4; g++) {
        f32x4 v4 = {vv[g * 4], vv[g * 4 + 1], vv[g * 4 + 2], vv[g * 4 + 3]};
        *(f32x4*)&Of[rb + g * 4] = v4;
      }
    }
    if (flags & 1) {
      short8 hp[2], mp[2], lp[2];
#pragma unroll
      for (int g = 0; g < 2; g++)
#pragma unroll
        for (int e = 0; e < 8; e++) {
          short h, m, l; split3(vv[g * 8 + e], h, m, l);
          hp[g][e] = h; mp[g][e] = m; lp[g][e] = l;
        }
#pragma unroll
      for (int g = 0; g < 2; g++) {
        *(short8*)&Or[rb + g * 8] = hp[g];
        *(short8*)&Or[PP + rb + g * 8] = mp[g];
        *(short8*)&Or[2 * PP + rb + g * 8] = lp[g];
      }
    }
  }
}

// --------------------------------------------- fused chain (cooperative) ----
__global__ __launch_bounds__(NTHR) void chain_all(
    const float* __restrict__ A, const float* __restrict__ Bv,
    float* __restrict__ dout, u16* __restrict__ Tbf, float* __restrict__ BdV) {
  cg::grid_group grid = cg::this_grid();
  __shared__ __align__(16) char lraw[30720];

  // chain scratch layout inside d_out (fully overwritten by gemm_main later)
  float* Mf  = dout;
  float* A2f = Mf + PP;
  float* A3f = A2f + PP;
  float* A4f = A3f + PP;
  float* Ff  = A4f + PP;
  u16* Mr  = (u16*)(Ff + PP);
  u16* Mc  = Mr + 3 * PP;
  u16* A2r = Mc + 3 * PP;
  u16* A2c = A2r + 3 * PP;
  u16* A4r = A2c + 3 * PP;
  u16* P1r = A4r + 3 * PP;
  u16* P1c = P1r + 3 * PP;
  u16* P2r = P1c + 3 * PP;
  u16* P2c = P2r + 3 * PP;

  const float scale = 1.0f / 32768.0f;  // ||M||_1 = 65536 -> theta = 2
  // c[k] = 1/k!
  const float k0 = 1.f, k1 = 1.f, k2 = 0.5f, k3 = 1.f / 6.f, k4 = 1.f / 24.f,
      k5 = 1.f / 120.f, k6 = 1.f / 720.f, k7 = 1.f / 5040.f, k8 = 1.f / 40320.f,
      k9 = 1.f / 362880.f, k10 = 1.f / 3628800.f, k11 = 1.f / 39916800.f,
      k12 = 1.f / 479001600.f, k13 = 1.f / 6227020800.f,
      k14 = 1.f / 87178291200.f, k15 = 1.f / 1307674368000.f,
      k16 = 1.f / 20922789888000.f;

  // ---- build M (f32 + 3-plane bf16 rows/cols) ----
  {
    const int base = blockIdx.x * NTHR + threadIdx.x;
    for (int idx = base; idx < PP; idx += GSTRIDE) {
      int i = idx / PDIM, j = idx - i * PDIM;
      float v = 0.f;
      if (i < QDIM) {
        if (j < QDIM) v = A[i * QDIM + j] * scale;
        else if (j == QDIM) v = Bv[i] * scale;
      }
      Mf[idx] = v;
      short h, m, l; split3(v, h, m, l);
      Mr[idx] = (u16)h; Mr[PP + idx] = (u16)m; Mr[2 * PP + idx] = (u16)l;
      int t = j * PDIM + i;
      Mc[t] = (u16)h; Mc[PP + t] = (u16)m; Mc[2 * PP + t] = (u16)l;
    }
  }
  grid.sync();
  // A2 = M*M (rows+cols+f32); A3 = A2*M (f32 only); A4 = A2*A2 (rows+f32)
  gemm_stage(Mr, Mc, A2r, A2c, A2f, nullptr, nullptr, nullptr, 0, 0, 0, 0,
             1 | 2 | 4, lraw);
  grid.sync();
  gemm_stage(A2r, Mc, nullptr, nullptr, A3f, nullptr, nullptr, nullptr,
             0, 0, 0, 0, 4, lraw);
  grid.sync();
  gemm_stage(A2r, A2c, A4r, nullptr, A4f, nullptr, nullptr, nullptr,
             0, 0, 0, 0, 1 | 4, lraw);
  grid.sync();
  // ---- combine -> P1 (cols planes) ----
  {
    const int base = blockIdx.x * NTHR + threadIdx.x;
    for (int idx = base; idx < PP; idx += GSTRIDE) {
      int i = idx / PDIM, j = idx - i * PDIM;
      float v = k16 * A4f[idx] + k13 * Mf[idx] + k14 * A2f[idx] + k15 * A3f[idx];
      if (i == j) v += k12;
      short h, m, l; split3(v, h, m, l);
      int t = j * PDIM + i;
      P1c[t] = (u16)h; P1c[PP + t] = (u16)m; P1c[2 * PP + t] = (u16)l;
    }
  }
  grid.sync();
  gemm_stage(A4r, P1c, nullptr, P2c, nullptr, Mf, A2f, A3f,
             k8, k9, k10, k11, 2 | 8, lraw);
  grid.sync();
  gemm_stage(A4r, P2c, nullptr, P1c, nullptr, Mf, A2f, A3f,
             k4, k5, k6, k7, 2 | 8, lraw);
  grid.sync();
  gemm_stage(A4r, P1c, P2r, P2c, nullptr, Mf, A2f, A3f,
             k0, k1, k2, k3, 1 | 2 | 8, lraw);
  grid.sync();
  // ---- 15 squarings (last one only needs the f32 result) ----
  u16 *sr = P2r, *sc = P2c, *dr = P1r, *dc = P1c;
  for (int s = 0; s < 15; s++) {
    const int fl = (s == 14) ? 4 : (1 | 2);
    gemm_stage(sr, sc, dr, dc, Ff, nullptr, nullptr, nullptr, 0, 0, 0, 0, fl,
               lraw);
    grid.sync();
    u16* t;
    t = sr; sr = dr; dr = t;
    t = sc; sc = dc; dc = t;
  }
  // ---- conv: Ad -> bf16 (512x512), Bd column -> f32 ----
  {
    const int base = blockIdx.x * NTHR + threadIdx.x;
    for (int idx = base; idx < QDIM * QDIM; idx += GSTRIDE) {
      int r = idx >> 9, cc = idx & 511;
      Tbf[idx] = (u16)f2bf(Ff[r * PDIM + cc]);
      if (cc == 0) BdV[r] = Ff[r * PDIM + QDIM];
    }
  }
}

// ----------------------------------------------------------- main GEMM ------
// out[q][n] = sum_k Ad[q][k] state[k][n] + Bd[q] x[n].  M=512/block, N=64.
// State loads + out stores nontemporal (keep Tb L2-resident, no RFO thrash).
__global__ __launch_bounds__(256, 2) void gemm_main(
    const u16* __restrict__ Tb, const float* __restrict__ Bd,
    const float* __restrict__ S, const float* __restrict__ xv,
    float* __restrict__ out0, float* __restrict__ out1) {
  __shared__ short Bs[2][64][LSTR];
  const int tid = threadIdx.x;
  const int lane = tid & 63, w = tid >> 6;
  const int l15 = lane & 15, quad = lane >> 4;
  const int n0 = blockIdx.x * 64;
  const int sn = tid & 63;
  const int sk = (tid >> 6) * 8;
  f32x4 acc[8][4] = {};
  float sreg[8];
#pragma unroll
  for (int r = 0; r < 8; r++)
    sreg[r] = __builtin_nontemporal_load(&S[(size_t)(sk + r) * NDIM + n0 + sn]);

  int buf = 0;
  for (int kb = 0; kb < QDIM; kb += 32) {
    {
      short8 pk;
#pragma unroll
      for (int r = 0; r < 8; r++) pk[r] = f2bf(sreg[r]);
      *(short8*)&Bs[buf][sn][sk] = pk;
    }
    __syncthreads();
    if (kb + 32 < QDIM) {
#pragma unroll
      for (int r = 0; r < 8; r++)
        sreg[r] = __builtin_nontemporal_load(
            &S[(size_t)(kb + 32 + sk + r) * NDIM + n0 + sn]);
    }
    short8 bfrag[4];
#pragma unroll
    for (int nt = 0; nt < 4; nt++)
      bfrag[nt] = *(const short8*)&Bs[buf][nt * 16 + l15][quad * 8];
    short8 afrag[8];
#pragma unroll
    for (int mt = 0; mt < 8; mt++)
      afrag[mt] = *(const short8*)&Tb[(size_t)(w * 128 + mt * 16 + l15) * QDIM +
                                      kb + quad * 8];
#pragma unroll
    for (int mt = 0; mt < 8; mt++)
#pragma unroll
      for (int nt = 0; nt < 4; nt++)
        acc[mt][nt] = MFMA(afrag[mt], bfrag[nt], acc[mt][nt]);
    buf ^= 1;
  }

  float xq[4];
#pragma unroll
  for (int nt = 0; nt < 4; nt++) xq[nt] = xv[n0 + nt * 16 + l15];
  f32x4 bd[8];
#pragma unroll
  for (int mt = 0; mt < 8; mt++)
    bd[mt] = *(const f32x4*)&Bd[w * 128 + mt * 16 + quad * 4];

  // out0 (column-major): mt-inner so both 64B halves of each 128B line are
  // written by adjacent instructions.  All stores nontemporal.
#pragma unroll
  for (int nt = 0; nt < 4; nt++) {
    const size_t cb = (size_t)(n0 + nt * 16 + l15) * QDIM + w * 128 + quad * 4;
#pragma unroll
    for (int mt = 0; mt < 8; mt++) {
      f32x4 v;
#pragma unroll
      for (int r = 0; r < 4; r++) v[r] = acc[mt][nt][r] + bd[mt][r] * xq[nt];
      __builtin_nontemporal_store(v, (f32x4*)&out0[cb + mt * 16]);
    }
  }
  // out1 (row-major): nt-inner, 4 adjacent 64B segments = 2 full lines
#pragma unroll
  for (int mt = 0; mt < 8; mt++)
#pragma unroll
    for (int r = 0; r < 4; r++) {
      const size_t rb = (size_t)(w * 128 + mt * 16 + quad * 4 + r) * NDIM + n0;
#pragma unroll
      for (int nt = 0; nt < 4; nt++) {
        float v = acc[mt][nt][r] + bd[mt][r] * xq[nt];
        __builtin_nontemporal_store(v, &out1[rb + nt * 16 + l15]);
      }
    }
}

// ---------------------------------------------------------------- launch ----
extern "C" void kernel_launch(void* const* d_in, const int* in_sizes, int n_in,
                              void* d_out, int out_size, void* d_ws, size_t ws_size,
                              hipStream_t stream) {
  const float* xv    = (const float*)d_in[0];
  const float* state = (const float*)d_in[1];
  const float* A     = (const float*)d_in[2];
  const float* Bv    = (const float*)d_in[3];
  float* out0 = (float*)d_out;
  float* out1 = out0 + (size_t)QDIM * NDIM;
  float* doutf = (float*)d_out;
  // ws: only the main-GEMM operands (must not overlap d_out)
  u16* Tbf = (u16*)d_ws;                         // 512x512 bf16
  float* BdV = (float*)(Tbf + QDIM * QDIM);      // 512 f32

  void* args[5];
  args[0] = (void*)&A;
  args[1] = (void*)&Bv;
  args[2] = (void*)&doutf;
  args[3] = (void*)&Tbf;
  args[4] = (void*)&BdV;
  hipLaunchCooperativeKernel((void*)chain_all, dim3(NBLK), dim3(NTHR), args, 0,
                             stream);
  gemm_main<<<dim3(NDIM / 64), 256, 0, stream>>>(Tbf, BdV, state, xv, out0, out1);

  (void)in_sizes; (void)n_in; (void)out_size; (void)ws_size;
}

// Round 3
// 1031.815 us; speedup vs baseline: 1.5197x; 1.5197x over previous
//
#include <hip/hip_runtime.h>

// LDN cell: new_state = expm(A) @ state + [inv(A)(expm(A)-I)B] x^T
// expm via scaling-and-squaring Taylor-16 (Paterson-Stockmeyer) on the
// augmented [[A,B],[0,0]] padded to 576 (theta=2, 15 squarings).
// Chain matrices stored as 3-plane bf16 (hi/mid/lo, f32-equivalent via 6 MFMA
// products) in BOTH orientations; chain scratch lives in d_out (fully
// overwritten by the final GEMM).
// ROUND 3 (round-2 resubmit after infra failure, de-risked):
//  - gemmP: BK=64 + double-buffered LDS (108 KB). Stage is latency-bound
//    (1 wave/SIMD, operands L2-cold after inter-stage flush); dbuf gives the
//    global prefetch a full-iteration latency window and halves the serial
//    iteration count (9 iters).
//  - gemm_main: 512-thread blocks, acc[4][4] (64 regs/lane) -> 16 waves/CU
//    at __launch_bounds__(512,2) WITHOUT spilling (the round-2 (256,4) was
//    register-infeasible: 128 acc regs vs 128-reg budget).

#define PDIM 576
#define PP (PDIM * PDIM)
#define QDIM 512
#define NDIM 65536
#define LSTR 40    // gemm_main LDS row stride in halfwords (80 B)
#define LSTR2 72   // gemmP LDS row stride in halfwords (144 B, 2-way-free banks)

typedef __attribute__((ext_vector_type(8))) short short8;
typedef __attribute__((ext_vector_type(4))) short short4v;
typedef __attribute__((ext_vector_type(4))) float f32x4;
typedef unsigned short u16;

__device__ __forceinline__ short f2bf(float f) {  // RNE bf16
  unsigned u = __builtin_bit_cast(unsigned, f);
  u += 0x7fffu + ((u >> 16) & 1u);
  return (short)(u >> 16);
}
__device__ __forceinline__ float bf2f(short s) {
  unsigned u = ((unsigned)(unsigned short)s) << 16;
  return __builtin_bit_cast(float, u);
}
__device__ __forceinline__ void split3(float v, short& h, short& m, short& l) {
  h = f2bf(v);
  float r1 = v - bf2f(h);
  m = f2bf(r1);
  float r2 = r1 - bf2f(m);
  l = f2bf(r2);
}
__device__ __forceinline__ f32x4 MFMA(short8 a, short8 b, f32x4 c) {
  return __builtin_amdgcn_mfma_f32_16x16x32_bf16(a, b, c, 0, 0, 0);
}

// --------------------------------------------------------------- build M ----
// Mf (f32), Mr/Mc (3-plane bf16 row-major / col-major) of [[A,B],[0,0]]*scale
__global__ __launch_bounds__(256) void build_MP(const float* __restrict__ A,
    const float* __restrict__ Bv, float* __restrict__ Mf,
    u16* __restrict__ Mr, u16* __restrict__ Mc, float scale) {
  int idx = blockIdx.x * 256 + threadIdx.x;
  int i = idx / PDIM, j = idx - i * PDIM;
  float v = 0.f;
  if (i < QDIM) {
    if (j < QDIM) v = A[i * QDIM + j] * scale;
    else if (j == QDIM) v = Bv[i] * scale;
  }
  Mf[idx] = v;
  short h, m, l; split3(v, h, m, l);
  Mr[idx] = (u16)h; Mr[PP + idx] = (u16)m; Mr[2 * PP + idx] = (u16)l;
  int t = j * PDIM + i;
  Mc[t] = (u16)h; Mc[PP + t] = (u16)m; Mc[2 * PP + t] = (u16)l;
}

// ------------------------------------------------- combine -> G3 (cols) -----
__global__ __launch_bounds__(256) void combineP(const float* __restrict__ A4f,
    const float* __restrict__ Mf, const float* __restrict__ A2f,
    const float* __restrict__ A3f, u16* __restrict__ Oc,
    float cA4, float cM, float cA2, float cA3, float cI) {
  int idx = blockIdx.x * 256 + threadIdx.x;
  int i = idx / PDIM, j = idx - i * PDIM;
  float v = cA4 * A4f[idx] + cM * Mf[idx] + cA2 * A2f[idx] + cA3 * A3f[idx];
  if (i == j) v += cI;
  short h, m, l; split3(v, h, m, l);
  int t = j * PDIM + i;
  Oc[t] = (u16)h; Oc[PP + t] = (u16)m; Oc[2 * PP + t] = (u16)l;
}

// ------------------------------------------- final: Ad bf16 + Bd f32 --------
__global__ __launch_bounds__(256) void conv_T(const float* __restrict__ Ff,
    u16* __restrict__ Tb, float* __restrict__ Bd) {
  int idx = blockIdx.x * 256 + threadIdx.x;
  int r = idx >> 9, c = idx & 511;
  Tb[idx] = (u16)f2bf(Ff[r * PDIM + c]);
  if (c == 0) Bd[r] = Ff[r * PDIM + QDIM];
}

// ------------------------------------------------- chain GEMM on planes -----
// Out = X*Y (+ cI*I + c1*E1 + c2*E2 + c3*E3).  X: row-major planes, Y:
// col-major planes.  flags: 1=write rows planes, 2=write cols planes,
// 4=write f32, 8=add E terms.  64x64 tile, 4 waves of 32x32.
// BK=64, double-buffered LDS: latency-bound stage (1 wave/SIMD, L2-cold
// operands) -> full-iteration prefetch window, 9 serial iterations.
__global__ __launch_bounds__(256) void gemmP(const u16* __restrict__ Xr,
    const u16* __restrict__ Yc, u16* __restrict__ Or, u16* __restrict__ Oc,
    float* __restrict__ Of, const float* __restrict__ E1,
    const float* __restrict__ E2, const float* __restrict__ E3,
    float cI, float c1, float c2, float c3, int flags) {
  // dbuf: Xs[2][3][64][LSTR2] + Ys[2][3][64][LSTR2] = 110592 B; tb aliases.
  __shared__ __align__(16) char lraw[110592];
  short (*Xs)[3][64][LSTR2] = (short(*)[3][64][LSTR2])lraw;
  short (*Ys)[3][64][LSTR2] = (short(*)[3][64][LSTR2])(lraw + 55296);
  float (*tb)[32][33] = (float(*)[32][33])lraw;
  const int tid = threadIdx.x;
  const int lane = tid & 63, w = tid >> 6;
  const int m0 = blockIdx.x * 64, n0 = blockIdx.y * 64;
  const int moff = (w >> 1) * 32, noff = (w & 1) * 32;
  const int l15 = lane & 15, quad = lane >> 4;
  f32x4 acc[2][2] = {};
  const int srow = tid >> 2, sk16 = (tid & 3) * 16;

  const u16* Xb = Xr + (size_t)(m0 + srow) * PDIM + sk16;
  const u16* Yb = Yc + (size_t)(n0 + srow) * PDIM + sk16;

  uint4 px[3][2], py[3][2];
#pragma unroll
  for (int pl = 0; pl < 3; pl++)
#pragma unroll
    for (int h = 0; h < 2; h++) {
      px[pl][h] = *(const uint4*)&Xb[(size_t)pl * PP + h * 8];
      py[pl][h] = *(const uint4*)&Yb[(size_t)pl * PP + h * 8];
    }
#pragma unroll
  for (int pl = 0; pl < 3; pl++)
#pragma unroll
    for (int h = 0; h < 2; h++) {
      *(uint4*)&Xs[0][pl][srow][sk16 + h * 8] = px[pl][h];
      *(uint4*)&Ys[0][pl][srow][sk16 + h * 8] = py[pl][h];
    }
#pragma unroll
  for (int pl = 0; pl < 3; pl++)
#pragma unroll
    for (int h = 0; h < 2; h++) {
      px[pl][h] = *(const uint4*)&Xb[(size_t)pl * PP + 64 + h * 8];
      py[pl][h] = *(const uint4*)&Yb[(size_t)pl * PP + 64 + h * 8];
    }
  __syncthreads();

  int cur = 0;
  for (int kb = 0; kb < PDIM; kb += 64) {
#pragma unroll
    for (int kh = 0; kh < 2; kh++) {
      short8 xa[3][2], yb2[3][2];
#pragma unroll
      for (int pl = 0; pl < 3; pl++) {
#pragma unroll
        for (int i = 0; i < 2; i++)
          xa[pl][i] =
              *(const short8*)&Xs[cur][pl][moff + i * 16 + l15][kh * 32 + quad * 8];
#pragma unroll
        for (int j = 0; j < 2; j++)
          yb2[pl][j] =
              *(const short8*)&Ys[cur][pl][noff + j * 16 + l15][kh * 32 + quad * 8];
      }
#pragma unroll
      for (int i = 0; i < 2; i++)
#pragma unroll
        for (int j = 0; j < 2; j++) {
          f32x4 a = acc[i][j];
          a = MFMA(xa[0][i], yb2[0][j], a);
          a = MFMA(xa[0][i], yb2[1][j], a);
          a = MFMA(xa[1][i], yb2[0][j], a);
          a = MFMA(xa[0][i], yb2[2][j], a);
          a = MFMA(xa[2][i], yb2[0][j], a);
          a = MFMA(xa[1][i], yb2[1][j], a);
          acc[i][j] = a;
        }
    }
    if (kb + 64 < PDIM) {
      // write prefetched tile to the inactive buffer (vmcnt wait lands here,
      // a full iteration after issue), then issue loads for kb+128
#pragma unroll
      for (int pl = 0; pl < 3; pl++)
#pragma unroll
        for (int h = 0; h < 2; h++) {
          *(uint4*)&Xs[cur ^ 1][pl][srow][sk16 + h * 8] = px[pl][h];
          *(uint4*)&Ys[cur ^ 1][pl][srow][sk16 + h * 8] = py[pl][h];
        }
      if (kb + 128 < PDIM) {
#pragma unroll
        for (int pl = 0; pl < 3; pl++)
#pragma unroll
          for (int h = 0; h < 2; h++) {
            px[pl][h] = *(const uint4*)&Xb[(size_t)pl * PP + kb + 128 + h * 8];
            py[pl][h] = *(const uint4*)&Yb[(size_t)pl * PP + kb + 128 + h * 8];
          }
      }
      __syncthreads();
      cur ^= 1;
    }
  }
  __syncthreads();  // tb aliases Xs buf0: all frag reads must be done

  // ---- epilogue ----
  if (flags & 8) {  // E-term additions (coalesced 4B reads, L2-hot)
#pragma unroll
    for (int i = 0; i < 2; i++)
#pragma unroll
      for (int j = 0; j < 2; j++)
#pragma unroll
        for (int r = 0; r < 4; r++) {
          const int grow = m0 + moff + i * 16 + quad * 4 + r;
          const int gcol = n0 + noff + j * 16 + l15;
          const size_t idx = (size_t)grow * PDIM + gcol;
          float add = c1 * E1[idx] + c2 * E2[idx] + c3 * E3[idx];
          if (grow == gcol) add += cI;
          acc[i][j][r] += add;
        }
  }
  if (flags & 2) {  // cols planes straight from C-layout (4 consecutive m)
#pragma unroll
    for (int i = 0; i < 2; i++)
#pragma unroll
      for (int j = 0; j < 2; j++) {
        short4v hv, mv, lv;
#pragma unroll
        for (int r = 0; r < 4; r++) {
          short h, m, l; split3(acc[i][j][r], h, m, l);
          hv[r] = h; mv[r] = m; lv[r] = l;
        }
        const size_t b = (size_t)(n0 + noff + j * 16 + l15) * PDIM +
                         m0 + moff + i * 16 + quad * 4;
        *(short4v*)&Oc[b] = hv;
        *(short4v*)&Oc[PP + b] = mv;
        *(short4v*)&Oc[2 * PP + b] = lv;
      }
  }
  if (flags & 5) {  // rows planes / f32 via per-wave LDS transpose
#pragma unroll
    for (int i = 0; i < 2; i++)
#pragma unroll
      for (int j = 0; j < 2; j++)
#pragma unroll
        for (int r = 0; r < 4; r++)
          tb[w][i * 16 + quad * 4 + r][j * 16 + l15] = acc[i][j][r];
    const int ml = lane & 31, ns = lane >> 5;
    float vv[16];
#pragma unroll
    for (int e = 0; e < 16; e++) vv[e] = tb[w][ml][ns * 16 + e];
    const size_t rb = (size_t)(m0 + moff + ml) * PDIM + n0 + noff + ns * 16;
    if (flags & 4) {
#pragma unroll
      for (int g = 0; g < 4; g++) {
        f32x4 v4 = {vv[g * 4], vv[g * 4 + 1], vv[g * 4 + 2], vv[g * 4 + 3]};
        *(f32x4*)&Of[rb + g * 4] = v4;
      }
    }
    if (flags & 1) {
      short8 hp[2], mp[2], lp[2];
#pragma unroll
      for (int g = 0; g < 2; g++)
#pragma unroll
        for (int e = 0; e < 8; e++) {
          short h, m, l; split3(vv[g * 8 + e], h, m, l);
          hp[g][e] = h; mp[g][e] = m; lp[g][e] = l;
        }
#pragma unroll
      for (int g = 0; g < 2; g++) {
        *(short8*)&Or[rb + g * 8] = hp[g];
        *(short8*)&Or[PP + rb + g * 8] = mp[g];
        *(short8*)&Or[2 * PP + rb + g * 8] = lp[g];
      }
    }
  }
}

// ----------------------------------------------------------- main GEMM ------
// out[q][n] = sum_k Ad[q][k] state[k][n] + Bd[q] x[n].  M=512/block, N=64.
// 512 threads (8 waves x 64 rows, acc[4][4]=64 regs/lane) -> 16 waves/CU at
// (512,2) without spill; round-0 showed latency-bound 2.36 TB/s @ 19.5% occ.
// State loads + out stores nontemporal (keep Tb L2-resident, no RFO thrash).
__global__ __launch_bounds__(512, 2) void gemm_main(
    const u16* __restrict__ Tb, const float* __restrict__ Bd,
    const float* __restrict__ S, const float* __restrict__ xv,
    float* __restrict__ out0, float* __restrict__ out1) {
  __shared__ __align__(16) short Bs[2][64][LSTR];
  const int tid = threadIdx.x;
  const int lane = tid & 63, w = tid >> 6;          // w in 0..7
  const int l15 = lane & 15, quad = lane >> 4;
  const int n0 = blockIdx.x * 64;
  const int sn = tid & 63;
  const int sk = (tid >> 6) * 4;                    // 4 k-rows per group
  f32x4 acc[4][4] = {};
  float sreg[4];
#pragma unroll
  for (int r = 0; r < 4; r++)
    sreg[r] = __builtin_nontemporal_load(&S[(size_t)(sk + r) * NDIM + n0 + sn]);

  int buf = 0;
  for (int kb = 0; kb < QDIM; kb += 32) {
    {
      short4v pk;
#pragma unroll
      for (int r = 0; r < 4; r++) pk[r] = f2bf(sreg[r]);
      *(short4v*)&Bs[buf][sn][sk] = pk;
    }
    __syncthreads();
    if (kb + 32 < QDIM) {
#pragma unroll
      for (int r = 0; r < 4; r++)
        sreg[r] = __builtin_nontemporal_load(
            &S[(size_t)(kb + 32 + sk + r) * NDIM + n0 + sn]);
    }
    short8 bfrag[4];
#pragma unroll
    for (int nt = 0; nt < 4; nt++)
      bfrag[nt] = *(const short8*)&Bs[buf][nt * 16 + l15][quad * 8];
    short8 afrag[4];
#pragma unroll
    for (int mt = 0; mt < 4; mt++)
      afrag[mt] = *(const short8*)&Tb[(size_t)(w * 64 + mt * 16 + l15) * QDIM +
                                      kb + quad * 8];
#pragma unroll
    for (int mt = 0; mt < 4; mt++)
#pragma unroll
      for (int nt = 0; nt < 4; nt++)
        acc[mt][nt] = MFMA(afrag[mt], bfrag[nt], acc[mt][nt]);
    buf ^= 1;
  }

  float xq[4];
#pragma unroll
  for (int nt = 0; nt < 4; nt++) xq[nt] = xv[n0 + nt * 16 + l15];
  f32x4 bd[4];
#pragma unroll
  for (int mt = 0; mt < 4; mt++)
    bd[mt] = *(const f32x4*)&Bd[w * 64 + mt * 16 + quad * 4];

  // out0 (column-major): mt-inner so both 64B halves of each 128B line are
  // written by adjacent instructions.  All stores nontemporal.
#pragma unroll
  for (int nt = 0; nt < 4; nt++) {
    const size_t cb = (size_t)(n0 + nt * 16 + l15) * QDIM + w * 64 + quad * 4;
#pragma unroll
    for (int mt = 0; mt < 4; mt++) {
      f32x4 v;
#pragma unroll
      for (int r = 0; r < 4; r++) v[r] = acc[mt][nt][r] + bd[mt][r] * xq[nt];
      __builtin_nontemporal_store(v, (f32x4*)&out0[cb + mt * 16]);
    }
  }
  // out1 (row-major): nt-inner, 4 adjacent 64B segments = 2 full lines
#pragma unroll
  for (int mt = 0; mt < 4; mt++)
#pragma unroll
    for (int r = 0; r < 4; r++) {
      const size_t rb = (size_t)(w * 64 + mt * 16 + quad * 4 + r) * NDIM + n0;
#pragma unroll
      for (int nt = 0; nt < 4; nt++) {
        float v = acc[mt][nt][r] + bd[mt][r] * xq[nt];
        __builtin_nontemporal_store(v, &out1[rb + nt * 16 + l15]);
      }
    }
}

// ---------------------------------------------------------------- launch ----
extern "C" void kernel_launch(void* const* d_in, const int* in_sizes, int n_in,
                              void* d_out, int out_size, void* d_ws, size_t ws_size,
                              hipStream_t stream) {
  const float* xv    = (const float*)d_in[0];
  const float* state = (const float*)d_in[1];
  const float* A     = (const float*)d_in[2];
  const float* Bv    = (const float*)d_in[3];
  float* out0 = (float*)d_out;
  float* out1 = out0 + (size_t)QDIM * NDIM;

  // Chain scratch lives in d_out (24.5 MB of 268 MB); every byte of d_out is
  // overwritten by gemm_main afterwards, and gemm_main reads only ws/inputs.
  float* Mf  = (float*)d_out;
  float* A2f = Mf + PP;
  float* A3f = A2f + PP;
  float* A4f = A3f + PP;
  float* Ff  = A4f + PP;
  u16* PL  = (u16*)(Ff + PP);
  u16* Mr  = PL;               // each plane-triple = 3*PP u16
  u16* Mc  = Mr + 3 * PP;
  u16* A2r = Mc + 3 * PP;
  u16* A2c = A2r + 3 * PP;
  u16* A4r = A2c + 3 * PP;
  u16* P1r = A4r + 3 * PP;
  u16* P1c = P1r + 3 * PP;
  u16* P2r = P1c + 3 * PP;
  u16* P2c = P2r + 3 * PP;
  // ws: only the main-GEMM operands (must not overlap d_out)
  u16* Tbf = (u16*)d_ws;                         // 512x512 bf16
  float* BdV = (float*)(Tbf + QDIM * QDIM);      // 512 f32

  const float scale = 1.0f / 32768.0f;  // ||M||_1 = 65536 -> theta = 2
  float c[17];
  { double f = 1.0; c[0] = 1.0f;
    for (int k = 1; k <= 16; k++) { f *= (double)k; c[k] = (float)(1.0 / f); } }

  dim3 g9(9, 9);
  build_MP<<<PP / 256, 256, 0, stream>>>(A, Bv, Mf, Mr, Mc, scale);
  // A2 = M*M (rows+cols+f32); A3 = A2*M (f32 only); A4 = A2*A2 (rows+f32)
  gemmP<<<g9, 256, 0, stream>>>(Mr, Mc, A2r, A2c, A2f,
                                nullptr, nullptr, nullptr, 0, 0, 0, 0, 1 | 2 | 4);
  gemmP<<<g9, 256, 0, stream>>>(A2r, Mc, nullptr, nullptr, A3f,
                                nullptr, nullptr, nullptr, 0, 0, 0, 0, 4);
  gemmP<<<g9, 256, 0, stream>>>(A2r, A2c, A4r, nullptr, A4f,
                                nullptr, nullptr, nullptr, 0, 0, 0, 0, 1 | 4);
  combineP<<<PP / 256, 256, 0, stream>>>(A4f, Mf, A2f, A3f, P1c,
                                         c[16], c[13], c[14], c[15], c[12]);
  gemmP<<<g9, 256, 0, stream>>>(A4r, P1c, nullptr, P2c, nullptr,
                                Mf, A2f, A3f, c[8], c[9], c[10], c[11], 2 | 8);
  gemmP<<<g9, 256, 0, stream>>>(A4r, P2c, nullptr, P1c, nullptr,
                                Mf, A2f, A3f, c[4], c[5], c[6], c[7], 2 | 8);
  gemmP<<<g9, 256, 0, stream>>>(A4r, P1c, P2r, P2c, nullptr,
                                Mf, A2f, A3f, c[0], c[1], c[2], c[3], 1 | 2 | 8);
  u16 *sr = P2r, *sc = P2c, *dr = P1r, *dc = P1c;
  for (int i = 0; i < 15; i++) {
    const int fl = (i == 14) ? 4 : (1 | 2);
    gemmP<<<g9, 256, 0, stream>>>(sr, sc, dr, dc, Ff,
                                  nullptr, nullptr, nullptr, 0, 0, 0, 0, fl);
    u16* t;
    t = sr; sr = dr; dr = t;
    t = sc; sc = dc; dc = t;
  }
  conv_T<<<(QDIM * QDIM) / 256, 256, 0, stream>>>(Ff, Tbf, BdV);
  gemm_main<<<dim3(NDIM / 64), 512, 0, stream>>>(Tbf, BdV, state, xv, out0, out1);

  (void)in_sizes; (void)n_in; (void)out_size; (void)ws_size;
}